// Round 3
// baseline (8278.970 us; speedup 1.0000x reference)
//
#include <hip/hip_runtime.h>
#include <math.h>

typedef __attribute__((ext_vector_type(8))) short s8v;   // 8 bf16 (A/B frag)
typedef __attribute__((ext_vector_type(4))) float f4v;   // 4 fp32 (C/D frag)
typedef unsigned long long u64;

#define TT 512
#define UU 1024
#define HHALF 32768u             // u32 per half-slot: 32 batches x 1024 units

// ---- ws byte offsets ----
#define B_TZ   0ull              // fp32 tz[v][u][g]  16 MB
#define B_A0H  16777216ull       // A0 hi frags  8 MB
#define B_A0L  25165824ull
#define B_A1H  33554432ull       // A1 hi frags 16 MB
#define B_A1L  50331648ull
#define B_H    67108864ull       // 12 half-slots x 128 KB = 1.5 MB
#define B_BAR  (B_H + 12ull*HHALF*4ull)   // barrier block (16 KB: 4 chains x 4 KB)

__device__ __forceinline__ unsigned short f2bf(float x) {
  unsigned u = __float_as_uint(x);
  return (unsigned short)((u + 0x7fffu + ((u >> 16) & 1u)) >> 16);
}

#define MFMA(a, b, c) __builtin_amdgcn_mfma_f32_16x16x32_bf16((a), (b), (c), 0, 0, 0)

__device__ __forceinline__ u64 ldsc(const u64* p) {
  return __hip_atomic_load(p, __ATOMIC_RELAXED, __HIP_MEMORY_SCOPE_AGENT);
}
__device__ __forceinline__ void stsc(u64* p, u64 v) {
  __hip_atomic_store(p, v, __ATOMIC_RELAXED, __HIP_MEMORY_SCOPE_AGENT);
}

// fast gates: v_exp + v_rcp (err ~1e-7, far below bf16 hi/lo truncation)
__device__ __forceinline__ float sigm(float x) {
  return __builtin_amdgcn_rcpf(1.f + __expf(-x));
}
__device__ __forceinline__ float tanha(float x) {
  return 1.f - 2.f * __builtin_amdgcn_rcpf(1.f + __expf(x + x));
}

// unpack 8 units (16 u32 as 4 u64, each u32 = hi16<<16 | lo16) into hi/lo frags
__device__ __forceinline__ void unpack8q(const u64* q, s8v& bh, s8v& bl) {
  union { uint4 u; s8v s; } H, L;
  H.u.x = __builtin_amdgcn_perm((unsigned)(q[0] >> 32), (unsigned)q[0], 0x07060302u);
  H.u.y = __builtin_amdgcn_perm((unsigned)(q[1] >> 32), (unsigned)q[1], 0x07060302u);
  H.u.z = __builtin_amdgcn_perm((unsigned)(q[2] >> 32), (unsigned)q[2], 0x07060302u);
  H.u.w = __builtin_amdgcn_perm((unsigned)(q[3] >> 32), (unsigned)q[3], 0x07060302u);
  L.u.x = __builtin_amdgcn_perm((unsigned)(q[0] >> 32), (unsigned)q[0], 0x05040100u);
  L.u.y = __builtin_amdgcn_perm((unsigned)(q[1] >> 32), (unsigned)q[1], 0x05040100u);
  L.u.z = __builtin_amdgcn_perm((unsigned)(q[2] >> 32), (unsigned)q[2], 0x05040100u);
  L.u.w = __builtin_amdgcn_perm((unsigned)(q[3] >> 32), (unsigned)q[3], 0x05040100u);
  bh = H.s; bl = L.s;
}

// ---------------- A-fragment pack kernels (unchanged) ----------------
__global__ __launch_bounds__(256) void pack_a0_k(const float* __restrict__ U0,
                                                 unsigned short* __restrict__ A0h,
                                                 unsigned short* __restrict__ A0l) {
  unsigned e = blockIdx.x * 256u + threadIdx.x;          // < 4M
  unsigned j = e & 7u, lane = (e >> 3) & 63u, ch = (e >> 9) & 3u;
  unsigned wv = (e >> 11) & 7u, wg = e >> 14;
  unsigned quad = lane >> 4, col = lane & 15u;
  unsigned k = wv * 128u + ch * 32u + quad * 8u + j;
  unsigned c = (col & 3u) * 1024u + wg * 4u + (col >> 2);
  float x = U0[(size_t)k * 4096u + c];
  unsigned short h = f2bf(x);
  A0h[e] = h;
  A0l[e] = f2bf(x - __uint_as_float(((unsigned)h) << 16));
}

__global__ __launch_bounds__(256) void pack_a1_k(const float* __restrict__ W1,
                                                 const float* __restrict__ U1,
                                                 unsigned short* __restrict__ A1h,
                                                 unsigned short* __restrict__ A1l) {
  unsigned e = blockIdx.x * 256u + threadIdx.x;          // < 8M
  unsigned j = e & 7u, lane = (e >> 3) & 63u, ch = (e >> 9) & 7u;
  unsigned wv = (e >> 12) & 7u, wg = e >> 15;
  unsigned quad = lane >> 4, col = lane & 15u;
  unsigned k = wv * 128u + (ch & 3u) * 32u + quad * 8u + j;
  unsigned c = (col & 3u) * 1024u + wg * 4u + (col >> 2);
  float x = (ch < 4u) ? W1[(size_t)k * 4096u + c] : U1[(size_t)k * 4096u + c];
  unsigned short h = f2bf(x);
  A1h[e] = h;
  A1l[e] = f2bf(x - __uint_as_float(((unsigned)h) << 16));
}

// ---------------- tz = embed @ W0 + b0, stored [v][u][g] (unchanged) ----------------
__global__ __launch_bounds__(256) void tz_gemm_k(const float* __restrict__ embed,
                                                 const float* __restrict__ W0,
                                                 const float* __restrict__ b0,
                                                 float* __restrict__ tz) {
  const int c0 = blockIdx.x << 6;
  const int v0 = blockIdx.y << 6;
  __shared__ float As[32][65];
  __shared__ float Bs[32][65];
  const int tid = threadIdx.x;
  const int tr = tid >> 4, tc = tid & 15;
  float acc[4][4];
#pragma unroll
  for (int r = 0; r < 4; ++r)
#pragma unroll
    for (int c = 0; c < 4; ++c) acc[r][c] = 0.f;

  for (int kc = 0; kc < 512; kc += 32) {
    __syncthreads();
    {
      int kk = tid & 31, vv = tid >> 5;
#pragma unroll
      for (int p = 0; p < 8; ++p)
        As[kk][vv + (p << 3)] = embed[(size_t)(v0 + vv + (p << 3)) * 512 + kc + kk];
    }
    {
      int cc = tid & 63, kk = tid >> 6;
#pragma unroll
      for (int p = 0; p < 8; ++p)
        Bs[kk + (p << 2)][cc] = W0[(size_t)(kc + kk + (p << 2)) * 4096 + c0 + cc];
    }
    __syncthreads();
#pragma unroll 8
    for (int kk = 0; kk < 32; ++kk) {
      float av[4], bv[4];
#pragma unroll
      for (int r = 0; r < 4; ++r) av[r] = As[kk][(tr << 2) + r];
#pragma unroll
      for (int c = 0; c < 4; ++c) bv[c] = Bs[kk][(tc << 2) + c];
#pragma unroll
      for (int r = 0; r < 4; ++r)
#pragma unroll
        for (int c = 0; c < 4; ++c) acc[r][c] = fmaf(av[r], bv[c], acc[r][c]);
    }
  }
#pragma unroll
  for (int r = 0; r < 4; ++r) {
    int v = v0 + (tr << 2) + r;
#pragma unroll
    for (int c = 0; c < 4; ++c) {
      int col = c0 + (tc << 2) + c;
      int g = col >> 10, u = col & 1023;
      tz[(size_t)v * 4096 + (u << 2) + g] = acc[r][c] + b0[col];
    }
  }
}

// ---------------- hierarchical barrier primitives ----------------
__device__ __forceinline__ void arrive(unsigned* cb, int grp) {
  unsigned old = __hip_atomic_fetch_add(cb + grp * 32, 1u, __ATOMIC_RELAXED,
                                        __HIP_MEMORY_SCOPE_AGENT);
  if ((old & 31u) == 31u) {
    unsigned o2 = __hip_atomic_fetch_add(cb + 512, 1u, __ATOMIC_RELAXED,
                                         __HIP_MEMORY_SCOPE_AGENT);
    if ((o2 & 7u) == 7u)
      __hip_atomic_store(cb + 576, (o2 >> 3) + 1u, __ATOMIC_RELAXED,
                         __HIP_MEMORY_SCOPE_AGENT);
  }
}
__device__ __forceinline__ void waitgen(unsigned* gen, unsigned target) {
  while (__hip_atomic_load(gen, __ATOMIC_RELAXED, __HIP_MEMORY_SCOPE_AGENT) < target)
    __builtin_amdgcn_s_sleep(1);
}

// ---------------- persistent MFMA LSTM ----------------
// 256 WGs x 512 thr (1/CU). WG owns 4 units of both layers; weights register-
// stationary (hi+lo bf16), shared across batches.
//
// KEY RESTRUCTURE (R3): the LSTM recurrence is independent per batch row, so
// the 64 batches split into two halves (A: 0-31, B: 32-63), each with its own
// h buffers and its own barrier chains. Per iteration the WG runs 4 phases
// {A0, B0, A1, B1}; between a chain's arrive and its next wait sit THREE other
// phases of compute, hiding the grid-barrier + MALL-broadcast latency that
// previously stalled everything (75% idle at R2).
//
// h broadcast: frag-packed per half-slot (32 batches x 1024 units, u32 each):
//   idx_u32(unit,batch) = (u>>5)*1024 + (b>>4)*512 + ((u>>2)&1)*256
//                         + (((u>>3)&3)*16 + (b&15))*4 + (u&3)
// Reader wave: contiguous u64 loads (MALL-coherent sc0sc1, no fences).
// Producer: sc0sc1 write-through + vmcnt(0) before arrive.
__global__ __launch_bounds__(512) void lstm_coop_k(const int* __restrict__ tokens,
                                                   const float* __restrict__ tz,
                                                   const unsigned short* __restrict__ A0h,
                                                   const unsigned short* __restrict__ A0l,
                                                   const unsigned short* __restrict__ A1h,
                                                   const unsigned short* __restrict__ A1l,
                                                   const float* __restrict__ b1,
                                                   unsigned* __restrict__ hbase,
                                                   float* __restrict__ out,
                                                   unsigned* __restrict__ bar) {
  __shared__ float zpf[4224];               // [gate]*1056 + [unit]*264 + [wave]*32 + b
  __shared__ unsigned hx[160];              // h staging [batch(32)][unit(4)+pad]

  const int tid = threadIdx.x;
  const int wg = blockIdx.x;
  const int lane = tid & 63;
  const int wv = __builtin_amdgcn_readfirstlane(tid >> 6);
  const int quad = lane >> 4, n = lane & 15;
  const int uj = tid >> 5;                  // unit idx (updaters, tid<128)
  const int ub = tid & 31;                  // batch-in-half (updaters)
  const int grp = wg & 7;
  const bool bt = (tid == 0);               // poller: wave 0 (decoupled from producer wave 7)

  unsigned* h0A = hbase;
  unsigned* h0B = hbase + 3 * HHALF;
  unsigned* h1A = hbase + 6 * HHALF;
  unsigned* h1B = hbase + 9 * HHALF;
  unsigned* cbA0 = bar;
  unsigned* cbB0 = bar + 1024;
  unsigned* cbA1 = bar + 2048;
  unsigned* cbB1 = bar + 3072;

  // ---- stationary weight fragments ----
  s8v a0h[4], a0l[4], a1h[8], a1l[8];
  {
    const s8v* p0h = (const s8v*)A0h + ((wg * 8 + wv) * 4) * 64 + lane;
    const s8v* p0l = (const s8v*)A0l + ((wg * 8 + wv) * 4) * 64 + lane;
#pragma unroll
    for (int ch = 0; ch < 4; ++ch) { a0h[ch] = p0h[ch * 64]; a0l[ch] = p0l[ch * 64]; }
    const s8v* p1h = (const s8v*)A1h + ((wg * 8 + wv) * 8) * 64 + lane;
    const s8v* p1l = (const s8v*)A1l + ((wg * 8 + wv) * 8) * 64 + lane;
#pragma unroll
    for (int ch = 0; ch < 8; ++ch) { a1h[ch] = p1h[ch * 64]; a1l[ch] = p1l[ch * 64]; }
  }

  float cs0A = 0.f, cs0B = 0.f, cs1A = 0.f, cs1B = 0.f;
  f4v b1v = {0.f, 0.f, 0.f, 0.f};
  if (tid < 128) {
    b1v.x = b1[0 * 1024 + wg * 4 + uj];
    b1v.y = b1[1 * 1024 + wg * 4 + uj];
    b1v.z = b1[2 * 1024 + wg * 4 + uj];
    b1v.w = b1[3 * 1024 + wg * 4 + uj];
  }

  // producer u32 base offset within a half-slot (batch/pair-independent part)
  const unsigned pcbb = ((unsigned)(wg >> 3) << 10) + ((unsigned)(wg & 1) << 8) +
                        (((unsigned)(wg >> 1) & 3u) << 6);

  // L0 pass: acc0 += U0*h, accW1 += W1*h (shared h-fragment loads)
  auto l0 = [&](const unsigned* hs, f4v* acc0, f4v* accw) {
    const u64* hb = (const u64*)hs;
#pragma unroll
    for (int ch = 0; ch < 4; ++ch) {
      const u64* p = hb + (((wv << 2) + ch) << 9) + (lane << 1);
      u64 q[2][4];
#pragma unroll
      for (int t = 0; t < 2; ++t) {
        q[t][0] = ldsc(p + (t << 8));
        q[t][1] = ldsc(p + (t << 8) + 1);
        q[t][2] = ldsc(p + (t << 8) + 128);
        q[t][3] = ldsc(p + (t << 8) + 129);
      }
#pragma unroll
      for (int t = 0; t < 2; ++t) {
        s8v bh, bl; unpack8q(q[t], bh, bl);
        acc0[t] = MFMA(a0h[ch], bh, acc0[t]);
        accw[t] = MFMA(a1h[ch], bh, accw[t]);
        acc0[t] = MFMA(a0l[ch], bh, acc0[t]);
        accw[t] = MFMA(a1l[ch], bh, accw[t]);
        acc0[t] = MFMA(a0h[ch], bl, acc0[t]);
        accw[t] = MFMA(a1h[ch], bl, accw[t]);
      }
    }
  };

  // L1 pass: acc += U1*h
  auto l1 = [&](const unsigned* hs, f4v* acc) {
    const u64* hb = (const u64*)hs;
#pragma unroll
    for (int ch = 0; ch < 4; ++ch) {
      const u64* p = hb + (((wv << 2) + ch) << 9) + (lane << 1);
      u64 q[2][4];
#pragma unroll
      for (int t = 0; t < 2; ++t) {
        q[t][0] = ldsc(p + (t << 8));
        q[t][1] = ldsc(p + (t << 8) + 1);
        q[t][2] = ldsc(p + (t << 8) + 128);
        q[t][3] = ldsc(p + (t << 8) + 129);
      }
#pragma unroll
      for (int t = 0; t < 2; ++t) {
        s8v bh, bl; unpack8q(q[t], bh, bl);
        acc[t] = MFMA(a1h[4 + ch], bh, acc[t]);
        acc[t] = MFMA(a1l[4 + ch], bh, acc[t]);
        acc[t] = MFMA(a1h[4 + ch], bl, acc[t]);
      }
    }
  };

  // phase tail: cross-wave reduce, gates, h pack+store, arrive. Returns h (updaters).
  auto tail = [&](f4v* acc, f4v bias, float& cst, unsigned* hslot, unsigned* cb) -> float {
#pragma unroll
    for (int t = 0; t < 2; ++t)
#pragma unroll
      for (int r = 0; r < 4; ++r)
        zpf[r * 1056 + quad * 264 + (wv << 5) + t * 16 + n] = acc[t][r];
    __syncthreads();
    float ho = 0.f;
    if (tid < 128) {
      f4v s = bias;
#pragma unroll
      for (int g = 0; g < 4; ++g) {
        float x = 0.f;
#pragma unroll
        for (int w = 0; w < 8; ++w) x += zpf[g * 1056 + uj * 264 + (w << 5) + ub];
        s[g] += x;
      }
      float iG = sigm(s.x);
      float fG = sigm(s.y);
      float gG = tanha(s.z);
      float oG = sigm(s.w);
      cst = fG * cst + iG * gG;
      ho = oG * tanha(cst);
      unsigned hb16 = (unsigned)f2bf(ho);
      unsigned lo16 = (unsigned)f2bf(ho - __uint_as_float(hb16 << 16));
      hx[ub * 5 + uj] = (hb16 << 16) | lo16;
    }
    __syncthreads();
    if (wv == 7) {
      int b = lane >> 1, pr = lane & 1;
      unsigned v0 = hx[b * 5 + pr * 2];
      unsigned v1 = hx[b * 5 + pr * 2 + 1];
      u64* p = (u64*)(hslot + pcbb + ((b >> 4) << 9) + ((b & 15) << 2) + (pr << 1));
      stsc(p, (u64)v0 | ((u64)v1 << 32));
      asm volatile("s_waitcnt vmcnt(0)" ::: "memory");
      if (lane == 0) arrive(cb, grp);
    }
    return ho;
  };

  for (int ss = 0; ss <= TT; ++ss) {
    const int s0w = ss % 3, s0r = (ss + 2) % 3;
    const int s1w = (ss + 2) % 3, s1r = (ss + 1) % 3;

    // prefetch tz for both halves (independent of all barriers)
    f4v tzvA = {0.f, 0.f, 0.f, 0.f}, tzvB = {0.f, 0.f, 0.f, 0.f};
    if (ss < TT && tid < 128) {
      tzvA = ((const f4v*)tz)[(size_t)tokens[ub * TT + ss] * 1024 + (wg << 2) + uj];
      tzvB = ((const f4v*)tz)[(size_t)tokens[(ub + 32) * TT + ss] * 1024 + (wg << 2) + uj];
    }

    // ======== P_A0: layer 0, half A ========
    if (bt) waitgen(cbA0 + 576, (unsigned)ss);
    __syncthreads();
    f4v acc0[2], w1A[2];
#pragma unroll
    for (int t = 0; t < 2; ++t) { acc0[t] = (f4v){0,0,0,0}; w1A[t] = (f4v){0,0,0,0}; }
    l0(h0A + s0r * HHALF, acc0, w1A);
    if (ss < TT) (void)tail(acc0, tzvA, cs0A, h0A + s0w * HHALF, cbA0);

    // ======== P_B0: layer 0, half B ========
    if (bt) waitgen(cbB0 + 576, (unsigned)ss);
    __syncthreads();
    f4v acc0b[2], w1B[2];
#pragma unroll
    for (int t = 0; t < 2; ++t) { acc0b[t] = (f4v){0,0,0,0}; w1B[t] = (f4v){0,0,0,0}; }
    l0(h0B + s0r * HHALF, acc0b, w1B);
    if (ss < TT) (void)tail(acc0b, tzvB, cs0B, h0B + s0w * HHALF, cbB0);

    // ======== P_A1: layer 1, half A ========
    if (bt && ss >= 1) waitgen(cbA1 + 576, (unsigned)(ss - 1));
    __syncthreads();
    if (ss >= 1) {
      l1(h1A + s1r * HHALF, w1A);
      float ho = tail(w1A, b1v, cs1A, h1A + s1w * HHALF, cbA1);
      if (tid < 128)
        out[(size_t)ub * (TT * UU) + (size_t)(ss - 1) * UU + (wg << 2) + uj] = ho;
    }

    // ======== P_B1: layer 1, half B ========
    if (bt && ss >= 1) waitgen(cbB1 + 576, (unsigned)(ss - 1));
    __syncthreads();
    if (ss >= 1) {
      l1(h1B + s1r * HHALF, w1B);
      float ho = tail(w1B, b1v, cs1B, h1B + s1w * HHALF, cbB1);
      if (tid < 128)
        out[(size_t)(ub + 32) * (TT * UU) + (size_t)(ss - 1) * UU + (wg << 2) + uj] = ho;
    }
  }
}

// ---------------- host ----------------
extern "C" void kernel_launch(void* const* d_in, const int* in_sizes, int n_in,
                              void* d_out, int out_size, void* d_ws, size_t ws_size,
                              hipStream_t stream) {
  const int*   tokens = (const int*)d_in[0];
  const float* embed  = (const float*)d_in[1];
  const float* W0     = (const float*)d_in[2];
  const float* U0     = (const float*)d_in[3];
  const float* b0     = (const float*)d_in[4];
  const float* W1     = (const float*)d_in[5];
  const float* U1     = (const float*)d_in[6];
  const float* b1     = (const float*)d_in[7];
  char* ws = (char*)d_ws;
  float*          tz  = (float*)(ws + B_TZ);
  unsigned short* A0h = (unsigned short*)(ws + B_A0H);
  unsigned short* A0l = (unsigned short*)(ws + B_A0L);
  unsigned short* A1h = (unsigned short*)(ws + B_A1H);
  unsigned short* A1l = (unsigned short*)(ws + B_A1L);
  unsigned*       hb  = (unsigned*)(ws + B_H);
  unsigned*       bar = (unsigned*)(ws + B_BAR);
  float* out = (float*)d_out;

  // zero h slots + barrier block (ws poisoned 0xAA before every call)
  hipMemsetAsync(ws + B_H, 0, (size_t)(12ull * HHALF * 4ull + 16384ull), stream);

  pack_a0_k<<<16384, 256, 0, stream>>>(U0, A0h, A0l);
  pack_a1_k<<<32768, 256, 0, stream>>>(W1, U1, A1h, A1l);
  tz_gemm_k<<<dim3(64, 16), 256, 0, stream>>>(embed, W0, b0, tz);

  void* args[] = {(void*)&tokens, (void*)&tz, (void*)&A0h, (void*)&A0l,
                  (void*)&A1h, (void*)&A1l, (void*)&b1, (void*)&hb,
                  (void*)&out, (void*)&bar};
  hipLaunchCooperativeKernel((void*)lstm_coop_k, dim3(256), dim3(512), args, 0, stream);
}

// Round 4
// 6576.035 us; speedup vs baseline: 1.2590x; 1.2590x over previous
//
#include <hip/hip_runtime.h>
#include <math.h>

typedef __attribute__((ext_vector_type(8))) short s8v;   // 8 bf16 (A/B frag)
typedef __attribute__((ext_vector_type(4))) float f4v;   // 4 fp32 (C/D frag)
typedef unsigned long long u64;

#define TT 512
#define UU 1024
#define HSZ 65536u               // u32 per h slot: [64 b][1024 u] frag-packed

// ---- ws byte offsets ----
#define B_TZ   0ull              // fp32 tz[v][u][g]  16 MB
#define B_A0H  16777216ull       // A0 hi frags  8 MB
#define B_A0L  25165824ull
#define B_A1H  33554432ull       // A1 hi frags 16 MB
#define B_A1L  50331648ull
#define B_H0   67108864ull       // h0 packed u32, 3 slots (768 KB)
#define B_H1   (B_H0 + 3ull*HSZ*4ull)
#define B_BAR  (B_H1 + 3ull*HSZ*4ull)   // barrier block (16 KB: 2 chains x 4 KB)

__device__ __forceinline__ unsigned short f2bf(float x) {
  unsigned u = __float_as_uint(x);
  return (unsigned short)((u + 0x7fffu + ((u >> 16) & 1u)) >> 16);
}

#define MFMA(a, b, c) __builtin_amdgcn_mfma_f32_16x16x32_bf16((a), (b), (c), 0, 0, 0)

__device__ __forceinline__ u64 ldsc(const u64* p) {
  return __hip_atomic_load(p, __ATOMIC_RELAXED, __HIP_MEMORY_SCOPE_AGENT);
}
__device__ __forceinline__ void stsc(u64* p, u64 v) {
  __hip_atomic_store(p, v, __ATOMIC_RELAXED, __HIP_MEMORY_SCOPE_AGENT);
}

// fast gates: v_exp + v_rcp (err ~1e-7, far below bf16 hi/lo truncation)
__device__ __forceinline__ float sigm(float x) {
  return __builtin_amdgcn_rcpf(1.f + __expf(-x));
}
__device__ __forceinline__ float tanha(float x) {
  return 1.f - 2.f * __builtin_amdgcn_rcpf(1.f + __expf(x + x));
}

// unpack 8 units (16 u32 as 4 u64, each u32 = hi16<<16 | lo16) into hi/lo frags
__device__ __forceinline__ void unpack8q(const u64* q, s8v& bh, s8v& bl) {
  union { uint4 u; s8v s; } H, L;
  H.u.x = __builtin_amdgcn_perm((unsigned)(q[0] >> 32), (unsigned)q[0], 0x07060302u);
  H.u.y = __builtin_amdgcn_perm((unsigned)(q[1] >> 32), (unsigned)q[1], 0x07060302u);
  H.u.z = __builtin_amdgcn_perm((unsigned)(q[2] >> 32), (unsigned)q[2], 0x07060302u);
  H.u.w = __builtin_amdgcn_perm((unsigned)(q[3] >> 32), (unsigned)q[3], 0x07060302u);
  L.u.x = __builtin_amdgcn_perm((unsigned)(q[0] >> 32), (unsigned)q[0], 0x05040100u);
  L.u.y = __builtin_amdgcn_perm((unsigned)(q[1] >> 32), (unsigned)q[1], 0x05040100u);
  L.u.z = __builtin_amdgcn_perm((unsigned)(q[2] >> 32), (unsigned)q[2], 0x05040100u);
  L.u.w = __builtin_amdgcn_perm((unsigned)(q[3] >> 32), (unsigned)q[3], 0x05040100u);
  bh = H.s; bl = L.s;
}

// ---------------- A-fragment pack kernels (unchanged) ----------------
__global__ __launch_bounds__(256) void pack_a0_k(const float* __restrict__ U0,
                                                 unsigned short* __restrict__ A0h,
                                                 unsigned short* __restrict__ A0l) {
  unsigned e = blockIdx.x * 256u + threadIdx.x;          // < 4M
  unsigned j = e & 7u, lane = (e >> 3) & 63u, ch = (e >> 9) & 3u;
  unsigned wv = (e >> 11) & 7u, wg = e >> 14;
  unsigned quad = lane >> 4, col = lane & 15u;
  unsigned k = wv * 128u + ch * 32u + quad * 8u + j;
  unsigned c = (col & 3u) * 1024u + wg * 4u + (col >> 2);
  float x = U0[(size_t)k * 4096u + c];
  unsigned short h = f2bf(x);
  A0h[e] = h;
  A0l[e] = f2bf(x - __uint_as_float(((unsigned)h) << 16));
}

__global__ __launch_bounds__(256) void pack_a1_k(const float* __restrict__ W1,
                                                 const float* __restrict__ U1,
                                                 unsigned short* __restrict__ A1h,
                                                 unsigned short* __restrict__ A1l) {
  unsigned e = blockIdx.x * 256u + threadIdx.x;          // < 8M
  unsigned j = e & 7u, lane = (e >> 3) & 63u, ch = (e >> 9) & 7u;
  unsigned wv = (e >> 12) & 7u, wg = e >> 15;
  unsigned quad = lane >> 4, col = lane & 15u;
  unsigned k = wv * 128u + (ch & 3u) * 32u + quad * 8u + j;
  unsigned c = (col & 3u) * 1024u + wg * 4u + (col >> 2);
  float x = (ch < 4u) ? W1[(size_t)k * 4096u + c] : U1[(size_t)k * 4096u + c];
  unsigned short h = f2bf(x);
  A1h[e] = h;
  A1l[e] = f2bf(x - __uint_as_float(((unsigned)h) << 16));
}

// ---------------- tz = embed @ W0 + b0, stored [v][u][g] (unchanged) ----------------
__global__ __launch_bounds__(256) void tz_gemm_k(const float* __restrict__ embed,
                                                 const float* __restrict__ W0,
                                                 const float* __restrict__ b0,
                                                 float* __restrict__ tz) {
  const int c0 = blockIdx.x << 6;
  const int v0 = blockIdx.y << 6;
  __shared__ float As[32][65];
  __shared__ float Bs[32][65];
  const int tid = threadIdx.x;
  const int tr = tid >> 4, tc = tid & 15;
  float acc[4][4];
#pragma unroll
  for (int r = 0; r < 4; ++r)
#pragma unroll
    for (int c = 0; c < 4; ++c) acc[r][c] = 0.f;

  for (int kc = 0; kc < 512; kc += 32) {
    __syncthreads();
    {
      int kk = tid & 31, vv = tid >> 5;
#pragma unroll
      for (int p = 0; p < 8; ++p)
        As[kk][vv + (p << 3)] = embed[(size_t)(v0 + vv + (p << 3)) * 512 + kc + kk];
    }
    {
      int cc = tid & 63, kk = tid >> 6;
#pragma unroll
      for (int p = 0; p < 8; ++p)
        Bs[kk + (p << 2)][cc] = W0[(size_t)(kc + kk + (p << 2)) * 4096 + c0 + cc];
    }
    __syncthreads();
#pragma unroll 8
    for (int kk = 0; kk < 32; ++kk) {
      float av[4], bv[4];
#pragma unroll
      for (int r = 0; r < 4; ++r) av[r] = As[kk][(tr << 2) + r];
#pragma unroll
      for (int c = 0; c < 4; ++c) bv[c] = Bs[kk][(tc << 2) + c];
#pragma unroll
      for (int r = 0; r < 4; ++r)
#pragma unroll
        for (int c = 0; c < 4; ++c) acc[r][c] = fmaf(av[r], bv[c], acc[r][c]);
    }
  }
#pragma unroll
  for (int r = 0; r < 4; ++r) {
    int v = v0 + (tr << 2) + r;
#pragma unroll
    for (int c = 0; c < 4; ++c) {
      int col = c0 + (tc << 2) + c;
      int g = col >> 10, u = col & 1023;
      tz[(size_t)v * 4096 + (u << 2) + g] = acc[r][c] + b0[col];
    }
  }
}

// ---------------- barrier primitives (wave-granular, replicated gen) ----------------
// chain block (u32): xc[grp*32] (8 groups), gc at 512, gen copies at 576 + k*16
__device__ __forceinline__ void arrive2(unsigned* cb, int grp) {
  unsigned old = __hip_atomic_fetch_add(cb + grp * 32, 1u, __ATOMIC_RELAXED,
                                        __HIP_MEMORY_SCOPE_AGENT);
  if ((old & 63u) == 63u) {                      // 32 WGs x 2 waves per group
    unsigned o2 = __hip_atomic_fetch_add(cb + 512, 1u, __ATOMIC_RELAXED,
                                         __HIP_MEMORY_SCOPE_AGENT);
    if ((o2 & 7u) == 7u) {
      unsigned g = (o2 >> 3) + 1u;
#pragma unroll
      for (int k = 0; k < 8; ++k)
        __hip_atomic_store(cb + 576 + k * 16, g, __ATOMIC_RELAXED,
                           __HIP_MEMORY_SCOPE_AGENT);
    }
  }
}
__device__ __forceinline__ void pollgen(const unsigned* g, unsigned target) {
  while (__hip_atomic_load(g, __ATOMIC_RELAXED, __HIP_MEMORY_SCOPE_AGENT) < target)
    __builtin_amdgcn_s_sleep(2);
  __builtin_amdgcn_sched_barrier(0);             // keep h loads after the poll
}

// ---------------- persistent MFMA LSTM ----------------
// 256 WGs x 512 thr (1/CU). 2 phases/step (R2 structure), overhead-slimmed:
//  - per-WAVE gen polling on replicated gen lines (no barrier thread, no
//    pre-phase syncthreads, no convoy through a single poller)
//  - ONE syncthreads per phase (after zpf writes); zpf double-buffered
//  - tails decentralized: waves 4,5 do layer-0 gates/store/arrive, waves 6,7
//    layer-1; 2 unit-batch pairs per lane, one u64 sc-store per lane; arrive
//    is wave-counted (2/WG/chain). hx staging LDS eliminated.
//  - zpf stride 65 kills the 8-way bank conflict of the w-reduce
//  - out[] stored as float2 per updater lane, after the drain
__global__ __launch_bounds__(512) void lstm_coop_k(const int* __restrict__ tokens,
                                                   const float* __restrict__ tz,
                                                   const unsigned short* __restrict__ A0h,
                                                   const unsigned short* __restrict__ A0l,
                                                   const unsigned short* __restrict__ A1h,
                                                   const unsigned short* __restrict__ A1l,
                                                   const float* __restrict__ b1,
                                                   unsigned* __restrict__ h0w,
                                                   unsigned* __restrict__ h1w,
                                                   float* __restrict__ out,
                                                   unsigned* __restrict__ bar) {
  __shared__ float zpf[2][8320];            // [buf][gate*2080 + unit*520 + wave*65 + b]

  const int tid = threadIdx.x;
  const int wg = blockIdx.x;
  const int lane = tid & 63;
  const int wv = __builtin_amdgcn_readfirstlane(tid >> 6);
  const int quad = lane >> 4, n = lane & 15;
  const int grp = wg & 7;
  const int j0 = (wv & 1) << 1;             // updater unit base (0 or 2)

  unsigned* cbA = bar;
  unsigned* cbB = bar + 1024;

  // ---- stationary weight fragments ----
  s8v a0h[4], a0l[4], a1h[8], a1l[8];
  {
    const s8v* p0h = (const s8v*)A0h + ((wg * 8 + wv) * 4) * 64 + lane;
    const s8v* p0l = (const s8v*)A0l + ((wg * 8 + wv) * 4) * 64 + lane;
#pragma unroll
    for (int ch = 0; ch < 4; ++ch) { a0h[ch] = p0h[ch * 64]; a0l[ch] = p0l[ch * 64]; }
    const s8v* p1h = (const s8v*)A1h + ((wg * 8 + wv) * 8) * 64 + lane;
    const s8v* p1l = (const s8v*)A1l + ((wg * 8 + wv) * 8) * 64 + lane;
#pragma unroll
    for (int ch = 0; ch < 8; ++ch) { a1h[ch] = p1h[ch * 64]; a1l[ch] = p1l[ch * 64]; }
  }

  // updater state: waves 4,5 hold c0 (layer 0); waves 6,7 hold c1 (layer 1)
  float cA0 = 0.f, cB0 = 0.f, cA1 = 0.f, cB1 = 0.f;
  f4v b1v0 = {0.f, 0.f, 0.f, 0.f}, b1v1 = {0.f, 0.f, 0.f, 0.f};
  if (wv >= 6) {
    b1v0.x = b1[0 * 1024 + wg * 4 + j0];
    b1v0.y = b1[1 * 1024 + wg * 4 + j0];
    b1v0.z = b1[2 * 1024 + wg * 4 + j0];
    b1v0.w = b1[3 * 1024 + wg * 4 + j0];
    b1v1.x = b1[0 * 1024 + wg * 4 + j0 + 1];
    b1v1.y = b1[1 * 1024 + wg * 4 + j0 + 1];
    b1v1.z = b1[2 * 1024 + wg * 4 + j0 + 1];
    b1v1.w = b1[3 * 1024 + wg * 4 + j0 + 1];
  }

  // producer u32 base: (wg>>3)*2048 + (b>>4)*512 + (wg&1)*256 + ((wg>>1)&3)*64 + (b&15)*4
  const unsigned pcbu = ((unsigned)(wg >> 3) << 11) + ((unsigned)(wg & 1) << 8) +
                        (((unsigned)(wg >> 1) & 3u) << 6) + ((unsigned)(lane >> 4) << 9) +
                        ((unsigned)(lane & 15) << 2);

  // K-slice MFMA fronts
  auto l0 = [&](const unsigned* hs, f4v* acc0, f4v* accw) {
    const u64* hb = (const u64*)hs;
#pragma unroll
    for (int ch = 0; ch < 4; ++ch) {
      const u64* p = hb + (((wv << 2) + ch) << 10) + (lane << 1);
      u64 q[4][4];
#pragma unroll
      for (int t = 0; t < 4; ++t) {
        q[t][0] = ldsc(p + (t << 8));
        q[t][1] = ldsc(p + (t << 8) + 1);
        q[t][2] = ldsc(p + (t << 8) + 128);
        q[t][3] = ldsc(p + (t << 8) + 129);
      }
#pragma unroll
      for (int t = 0; t < 4; ++t) {
        s8v bh, bl; unpack8q(q[t], bh, bl);
        acc0[t] = MFMA(a0h[ch], bh, acc0[t]);
        accw[t] = MFMA(a1h[ch], bh, accw[t]);
        acc0[t] = MFMA(a0l[ch], bh, acc0[t]);
        accw[t] = MFMA(a1l[ch], bh, accw[t]);
        acc0[t] = MFMA(a0h[ch], bl, acc0[t]);
        accw[t] = MFMA(a1h[ch], bl, accw[t]);
      }
    }
  };
  auto l1 = [&](const unsigned* hs, f4v* acc) {
    const u64* hb = (const u64*)hs;
#pragma unroll
    for (int ch = 0; ch < 4; ++ch) {
      const u64* p = hb + (((wv << 2) + ch) << 10) + (lane << 1);
      u64 q[4][4];
#pragma unroll
      for (int t = 0; t < 4; ++t) {
        q[t][0] = ldsc(p + (t << 8));
        q[t][1] = ldsc(p + (t << 8) + 1);
        q[t][2] = ldsc(p + (t << 8) + 128);
        q[t][3] = ldsc(p + (t << 8) + 129);
      }
#pragma unroll
      for (int t = 0; t < 4; ++t) {
        s8v bh, bl; unpack8q(q[t], bh, bl);
        acc[t] = MFMA(a1h[4 + ch], bh, acc[t]);
        acc[t] = MFMA(a1l[4 + ch], bh, acc[t]);
        acc[t] = MFMA(a1h[4 + ch], bl, acc[t]);
      }
    }
  };

  for (int ss = 0; ss <= TT; ++ss) {
    const int s0w = ss % 3, s0r = (ss + 2) % 3;         // h0 slots
    const int s1w = (ss + 2) % 3, s1r = (ss + 1) % 3;   // h1 slots

    // tz prefetch (layer-0 updater waves only; independent of all gens)
    f4v tz0 = {0.f, 0.f, 0.f, 0.f}, tz1 = {0.f, 0.f, 0.f, 0.f};
    if ((wv == 4 || wv == 5) && ss < TT) {
      size_t base = (size_t)tokens[lane * TT + ss] * 1024 + (wg << 2);
      tz0 = ((const f4v*)tz)[base + j0];
      tz1 = ((const f4v*)tz)[base + j0 + 1];
    }

    // ======== phase h0: acc0 = U0*h0(ss-1), accw = W1*h0(ss-1) ========
    pollgen(cbA + 576 + wv * 16, (unsigned)ss);
    f4v acc0[4], accw[4];
#pragma unroll
    for (int t = 0; t < 4; ++t) { acc0[t] = (f4v){0,0,0,0}; accw[t] = (f4v){0,0,0,0}; }
    l0(h0w + s0r * HSZ, acc0, accw);
#pragma unroll
    for (int t = 0; t < 4; ++t)
#pragma unroll
      for (int r = 0; r < 4; ++r)
        zpf[0][r * 2080 + quad * 520 + wv * 65 + t * 16 + n] = acc0[t][r];
    __syncthreads();

    if (ss < TT && (wv == 4 || wv == 5)) {
      // ---- tail0 (layer-0 update for units j0, j0+1; batch = lane) ----
      f4v s0 = tz0, s1 = tz1;
      const float* zb = zpf[0];
#pragma unroll
      for (int g = 0; g < 4; ++g) {
        float x0 = 0.f, x1 = 0.f;
#pragma unroll
        for (int w = 0; w < 8; ++w) {
          x0 += zb[g * 2080 + j0 * 520 + w * 65 + lane];
          x1 += zb[g * 2080 + (j0 + 1) * 520 + w * 65 + lane];
        }
        s0[g] += x0; s1[g] += x1;
      }
      float hA, hB;
      {
        float iG = sigm(s0.x), fG = sigm(s0.y), gG = tanha(s0.z), oG = sigm(s0.w);
        cA0 = fG * cA0 + iG * gG; hA = oG * tanha(cA0);
      }
      {
        float iG = sigm(s1.x), fG = sigm(s1.y), gG = tanha(s1.z), oG = sigm(s1.w);
        cB0 = fG * cB0 + iG * gG; hB = oG * tanha(cB0);
      }
      unsigned hiA = (unsigned)f2bf(hA);
      unsigned pA = (hiA << 16) | (unsigned)f2bf(hA - __uint_as_float(hiA << 16));
      unsigned hiB = (unsigned)f2bf(hB);
      unsigned pB = (hiB << 16) | (unsigned)f2bf(hB - __uint_as_float(hiB << 16));
      u64* p = (u64*)(h0w + s0w * HSZ) + (pcbu >> 1) + (wv & 1);
      stsc(p, (u64)pA | ((u64)pB << 32));
      asm volatile("s_waitcnt vmcnt(0)" ::: "memory");
      if (lane == 0) arrive2(cbA, grp);
    }

    // ======== phase h1: accw += U1*h1(ss-2); layer-1 gates ========
    if (ss >= 1) {
      pollgen(cbB + 576 + wv * 16, (unsigned)(ss - 1));
      l1(h1w + s1r * HSZ, accw);
#pragma unroll
      for (int t = 0; t < 4; ++t)
#pragma unroll
        for (int r = 0; r < 4; ++r)
          zpf[1][r * 2080 + quad * 520 + wv * 65 + t * 16 + n] = accw[t][r];
      __syncthreads();

      if (wv >= 6) {
        // ---- tail1 (layer-1 update for units j0, j0+1; batch = lane) ----
        f4v s0 = b1v0, s1 = b1v1;
        const float* zb = zpf[1];
#pragma unroll
        for (int g = 0; g < 4; ++g) {
          float x0 = 0.f, x1 = 0.f;
#pragma unroll
          for (int w = 0; w < 8; ++w) {
            x0 += zb[g * 2080 + j0 * 520 + w * 65 + lane];
            x1 += zb[g * 2080 + (j0 + 1) * 520 + w * 65 + lane];
          }
          s0[g] += x0; s1[g] += x1;
        }
        float hA, hB;
        {
          float iG = sigm(s0.x), fG = sigm(s0.y), gG = tanha(s0.z), oG = sigm(s0.w);
          cA1 = fG * cA1 + iG * gG; hA = oG * tanha(cA1);
        }
        {
          float iG = sigm(s1.x), fG = sigm(s1.y), gG = tanha(s1.z), oG = sigm(s1.w);
          cB1 = fG * cB1 + iG * gG; hB = oG * tanha(cB1);
        }
        unsigned hiA = (unsigned)f2bf(hA);
        unsigned pA = (hiA << 16) | (unsigned)f2bf(hA - __uint_as_float(hiA << 16));
        unsigned hiB = (unsigned)f2bf(hB);
        unsigned pB = (hiB << 16) | (unsigned)f2bf(hB - __uint_as_float(hiB << 16));
        u64* p = (u64*)(h1w + s1w * HSZ) + (pcbu >> 1) + (wv & 1);
        stsc(p, (u64)pA | ((u64)pB << 32));
        asm volatile("s_waitcnt vmcnt(0)" ::: "memory");
        if (lane == 0) arrive2(cbB, grp);
        // out store (plain cached, off the sync path)
        float2 ov; ov.x = hA; ov.y = hB;
        *(float2*)&out[(size_t)lane * (TT * UU) + (size_t)(ss - 1) * UU + (wg << 2) + j0] = ov;
      }
    } else {
      // ss==0: no phase h1 — still need a sync so zpf[0] isn't rewritten
      // by fast waves before tail0 reads it
      __syncthreads();
    }
  }
}

// ---------------- host ----------------
extern "C" void kernel_launch(void* const* d_in, const int* in_sizes, int n_in,
                              void* d_out, int out_size, void* d_ws, size_t ws_size,
                              hipStream_t stream) {
  const int*   tokens = (const int*)d_in[0];
  const float* embed  = (const float*)d_in[1];
  const float* W0     = (const float*)d_in[2];
  const float* U0     = (const float*)d_in[3];
  const float* b0     = (const float*)d_in[4];
  const float* W1     = (const float*)d_in[5];
  const float* U1     = (const float*)d_in[6];
  const float* b1     = (const float*)d_in[7];
  char* ws = (char*)d_ws;
  float*          tz  = (float*)(ws + B_TZ);
  unsigned short* A0h = (unsigned short*)(ws + B_A0H);
  unsigned short* A0l = (unsigned short*)(ws + B_A0L);
  unsigned short* A1h = (unsigned short*)(ws + B_A1H);
  unsigned short* A1l = (unsigned short*)(ws + B_A1L);
  unsigned*       h0w = (unsigned*)(ws + B_H0);
  unsigned*       h1w = (unsigned*)(ws + B_H1);
  unsigned*       bar = (unsigned*)(ws + B_BAR);
  float* out = (float*)d_out;

  // zero h slots + barrier block (ws poisoned 0xAA before every call)
  hipMemsetAsync(ws + B_H0, 0, (size_t)(6ull * HSZ * 4ull + 16384ull), stream);

  pack_a0_k<<<16384, 256, 0, stream>>>(U0, A0h, A0l);
  pack_a1_k<<<32768, 256, 0, stream>>>(W1, U1, A1h, A1l);
  tz_gemm_k<<<dim3(64, 16), 256, 0, stream>>>(embed, W0, b0, tz);

  void* args[] = {(void*)&tokens, (void*)&tz, (void*)&A0h, (void*)&A0l,
                  (void*)&A1h, (void*)&A1l, (void*)&b1, (void*)&h0w, (void*)&h1w,
                  (void*)&out, (void*)&bar};
  hipLaunchCooperativeKernel((void*)lstm_coop_k, dim3(256), dim3(512), args, 0, stream);
}

// Round 5
// 6303.931 us; speedup vs baseline: 1.3133x; 1.0432x over previous
//
#include <hip/hip_runtime.h>
#include <math.h>

typedef __attribute__((ext_vector_type(8))) short s8v;   // 8 bf16 (A/B frag)
typedef __attribute__((ext_vector_type(4))) float f4v;   // 4 fp32 (C/D frag)
typedef __attribute__((ext_vector_type(2))) float f2v;
typedef unsigned long long u64;

#define TT 512
#define UU 1024
#define HSZ 65536u               // u32 per h slot: [64 b][1024 u] frag-packed

// ---- ws byte offsets ----
#define B_TZ   0ull              // fp32 tz[v][u][g]  16 MB
#define B_A0H  16777216ull       // A0 hi frags  8 MB
#define B_A0L  25165824ull
#define B_A1H  33554432ull       // A1 hi frags 16 MB
#define B_A1L  50331648ull
#define B_H0   67108864ull       // h0 packed u32, 3 slots (768 KB)
#define B_H1   (B_H0 + 3ull*HSZ*4ull)
#define B_BAR  (B_H1 + 3ull*HSZ*4ull)   // barrier block (16 KB: 2 chains x 4 KB)

__device__ __forceinline__ unsigned short f2bf(float x) {
  unsigned u = __float_as_uint(x);
  return (unsigned short)((u + 0x7fffu + ((u >> 16) & 1u)) >> 16);
}

#define MFMA(a, b, c) __builtin_amdgcn_mfma_f32_16x16x32_bf16((a), (b), (c), 0, 0, 0)

__device__ __forceinline__ void stsc(u64* p, u64 v) {
  __hip_atomic_store(p, v, __ATOMIC_RELAXED, __HIP_MEMORY_SCOPE_AGENT);
}

// fast gates: v_exp + v_rcp (err ~1e-7, far below bf16 hi/lo truncation)
__device__ __forceinline__ float sigm(float x) {
  return __builtin_amdgcn_rcpf(1.f + __expf(-x));
}
__device__ __forceinline__ float tanha(float x) {
  return 1.f - 2.f * __builtin_amdgcn_rcpf(1.f + __expf(x + x));
}

// unpack 8 units (2 uint4, each u32 = hi16<<16 | lo16) into hi/lo bf16 frags
__device__ __forceinline__ void unpack8v(uint4 A, uint4 B, s8v& bh, s8v& bl) {
  union { uint4 u; s8v s; } H, L;
  H.u.x = __builtin_amdgcn_perm(A.y, A.x, 0x07060302u);
  H.u.y = __builtin_amdgcn_perm(A.w, A.z, 0x07060302u);
  H.u.z = __builtin_amdgcn_perm(B.y, B.x, 0x07060302u);
  H.u.w = __builtin_amdgcn_perm(B.w, B.z, 0x07060302u);
  L.u.x = __builtin_amdgcn_perm(A.y, A.x, 0x05040100u);
  L.u.y = __builtin_amdgcn_perm(A.w, A.z, 0x05040100u);
  L.u.z = __builtin_amdgcn_perm(B.y, B.x, 0x05040100u);
  L.u.w = __builtin_amdgcn_perm(B.w, B.z, 0x05040100u);
  bh = H.s; bl = L.s;
}

// ---------------- A-fragment pack kernels (unchanged) ----------------
__global__ __launch_bounds__(256) void pack_a0_k(const float* __restrict__ U0,
                                                 unsigned short* __restrict__ A0h,
                                                 unsigned short* __restrict__ A0l) {
  unsigned e = blockIdx.x * 256u + threadIdx.x;          // < 4M
  unsigned j = e & 7u, lane = (e >> 3) & 63u, ch = (e >> 9) & 3u;
  unsigned wv = (e >> 11) & 7u, wg = e >> 14;
  unsigned quad = lane >> 4, col = lane & 15u;
  unsigned k = wv * 128u + ch * 32u + quad * 8u + j;
  unsigned c = (col & 3u) * 1024u + wg * 4u + (col >> 2);
  float x = U0[(size_t)k * 4096u + c];
  unsigned short h = f2bf(x);
  A0h[e] = h;
  A0l[e] = f2bf(x - __uint_as_float(((unsigned)h) << 16));
}

__global__ __launch_bounds__(256) void pack_a1_k(const float* __restrict__ W1,
                                                 const float* __restrict__ U1,
                                                 unsigned short* __restrict__ A1h,
                                                 unsigned short* __restrict__ A1l) {
  unsigned e = blockIdx.x * 256u + threadIdx.x;          // < 8M
  unsigned j = e & 7u, lane = (e >> 3) & 63u, ch = (e >> 9) & 7u;
  unsigned wv = (e >> 12) & 7u, wg = e >> 15;
  unsigned quad = lane >> 4, col = lane & 15u;
  unsigned k = wv * 128u + (ch & 3u) * 32u + quad * 8u + j;
  unsigned c = (col & 3u) * 1024u + wg * 4u + (col >> 2);
  float x = (ch < 4u) ? W1[(size_t)k * 4096u + c] : U1[(size_t)k * 4096u + c];
  unsigned short h = f2bf(x);
  A1h[e] = h;
  A1l[e] = f2bf(x - __uint_as_float(((unsigned)h) << 16));
}

// ---------------- tz = embed @ W0 + b0, stored [v][u][g] (unchanged) ----------------
__global__ __launch_bounds__(256) void tz_gemm_k(const float* __restrict__ embed,
                                                 const float* __restrict__ W0,
                                                 const float* __restrict__ b0,
                                                 float* __restrict__ tz) {
  const int c0 = blockIdx.x << 6;
  const int v0 = blockIdx.y << 6;
  __shared__ float As[32][65];
  __shared__ float Bs[32][65];
  const int tid = threadIdx.x;
  const int tr = tid >> 4, tc = tid & 15;
  float acc[4][4];
#pragma unroll
  for (int r = 0; r < 4; ++r)
#pragma unroll
    for (int c = 0; c < 4; ++c) acc[r][c] = 0.f;

  for (int kc = 0; kc < 512; kc += 32) {
    __syncthreads();
    {
      int kk = tid & 31, vv = tid >> 5;
#pragma unroll
      for (int p = 0; p < 8; ++p)
        As[kk][vv + (p << 3)] = embed[(size_t)(v0 + vv + (p << 3)) * 512 + kc + kk];
    }
    {
      int cc = tid & 63, kk = tid >> 6;
#pragma unroll
      for (int p = 0; p < 8; ++p)
        Bs[kk + (p << 2)][cc] = W0[(size_t)(kc + kk + (p << 2)) * 4096 + c0 + cc];
    }
    __syncthreads();
#pragma unroll 8
    for (int kk = 0; kk < 32; ++kk) {
      float av[4], bv[4];
#pragma unroll
      for (int r = 0; r < 4; ++r) av[r] = As[kk][(tr << 2) + r];
#pragma unroll
      for (int c = 0; c < 4; ++c) bv[c] = Bs[kk][(tc << 2) + c];
#pragma unroll
      for (int r = 0; r < 4; ++r)
#pragma unroll
        for (int c = 0; c < 4; ++c) acc[r][c] = fmaf(av[r], bv[c], acc[r][c]);
    }
  }
#pragma unroll
  for (int r = 0; r < 4; ++r) {
    int v = v0 + (tr << 2) + r;
#pragma unroll
    for (int c = 0; c < 4; ++c) {
      int col = c0 + (tc << 2) + c;
      int g = col >> 10, u = col & 1023;
      tz[(size_t)v * 4096 + (u << 2) + g] = acc[r][c] + b0[col];
    }
  }
}

// ---------------- barrier primitives (wave-granular, replicated gen) ----------------
__device__ __forceinline__ void arrive2(unsigned* cb, int grp) {
  unsigned old = __hip_atomic_fetch_add(cb + grp * 32, 1u, __ATOMIC_RELAXED,
                                        __HIP_MEMORY_SCOPE_AGENT);
  if ((old & 63u) == 63u) {                      // 32 WGs x 2 waves per group
    unsigned o2 = __hip_atomic_fetch_add(cb + 512, 1u, __ATOMIC_RELAXED,
                                         __HIP_MEMORY_SCOPE_AGENT);
    if ((o2 & 7u) == 7u) {
      unsigned g = (o2 >> 3) + 1u;
#pragma unroll
      for (int k = 0; k < 8; ++k)
        __hip_atomic_store(cb + 576 + k * 16, g, __ATOMIC_RELAXED,
                           __HIP_MEMORY_SCOPE_AGENT);
    }
  }
}
__device__ __forceinline__ void pollgen(const unsigned* g, unsigned target) {
  while (__hip_atomic_load(g, __ATOMIC_RELAXED, __HIP_MEMORY_SCOPE_AGENT) < target)
    __builtin_amdgcn_s_sleep(2);
  asm volatile("" ::: "memory");                 // h loads are PLAIN now: no hoisting
  __builtin_amdgcn_sched_barrier(0);
}

// ---------------- persistent MFMA LSTM ----------------
// 256 WGs x 512 thr (1/CU). R4 structure; R5 change: h broadcast reads are
// PLAIN CACHED loads (uint4), so the 32 WGs of each XCD share one L2 copy:
// MALL read traffic drops 64 MB/phase -> ~2-6 MB/phase (the R4 bottleneck:
// 65.5 GB total / 6.6 ms = 10 TB/s = MALL-bound, pipes 16% busy).
// Coherence: producers write sc0sc1 through to MALL + vmcnt(0) before arrive
// (unchanged); consumers invalidate stale L1/L2 lines with ONE raw
// `buffer_inv sc1` per WG per step (wave 0, after poll B — at that point both
// slots read next are fully published at MALL; no address of a rotating slot
// is ever re-read between its write and the next inv, so every post-inv fill
// is fresh). No waitcnt drain on any other wave — this is NOT the R1 fence.
// out[] stores are nontemporal so L2 never holds dirty lines from this kernel.
__global__ __launch_bounds__(512) void lstm_coop_k(const int* __restrict__ tokens,
                                                   const float* __restrict__ tz,
                                                   const unsigned short* __restrict__ A0h,
                                                   const unsigned short* __restrict__ A0l,
                                                   const unsigned short* __restrict__ A1h,
                                                   const unsigned short* __restrict__ A1l,
                                                   const float* __restrict__ b1,
                                                   unsigned* __restrict__ h0w,
                                                   unsigned* __restrict__ h1w,
                                                   float* __restrict__ out,
                                                   unsigned* __restrict__ bar) {
  __shared__ float zpf[2][8320];            // [buf][gate*2080 + unit*520 + wave*65 + b]

  const int tid = threadIdx.x;
  const int wg = blockIdx.x;
  const int lane = tid & 63;
  const int wv = __builtin_amdgcn_readfirstlane(tid >> 6);
  const int quad = lane >> 4, n = lane & 15;
  const int grp = wg & 7;
  const int j0 = (wv & 1) << 1;             // updater unit base (0 or 2)

  unsigned* cbA = bar;
  unsigned* cbB = bar + 1024;

  // ---- stationary weight fragments ----
  s8v a0h[4], a0l[4], a1h[8], a1l[8];
  {
    const s8v* p0h = (const s8v*)A0h + ((wg * 8 + wv) * 4) * 64 + lane;
    const s8v* p0l = (const s8v*)A0l + ((wg * 8 + wv) * 4) * 64 + lane;
#pragma unroll
    for (int ch = 0; ch < 4; ++ch) { a0h[ch] = p0h[ch * 64]; a0l[ch] = p0l[ch * 64]; }
    const s8v* p1h = (const s8v*)A1h + ((wg * 8 + wv) * 8) * 64 + lane;
    const s8v* p1l = (const s8v*)A1l + ((wg * 8 + wv) * 8) * 64 + lane;
#pragma unroll
    for (int ch = 0; ch < 8; ++ch) { a1h[ch] = p1h[ch * 64]; a1l[ch] = p1l[ch * 64]; }
  }

  // updater state: waves 4,5 hold c0 (layer 0); waves 6,7 hold c1 (layer 1)
  float cA0 = 0.f, cB0 = 0.f, cA1 = 0.f, cB1 = 0.f;
  f4v b1v0 = {0.f, 0.f, 0.f, 0.f}, b1v1 = {0.f, 0.f, 0.f, 0.f};
  if (wv >= 6) {
    b1v0.x = b1[0 * 1024 + wg * 4 + j0];
    b1v0.y = b1[1 * 1024 + wg * 4 + j0];
    b1v0.z = b1[2 * 1024 + wg * 4 + j0];
    b1v0.w = b1[3 * 1024 + wg * 4 + j0];
    b1v1.x = b1[0 * 1024 + wg * 4 + j0 + 1];
    b1v1.y = b1[1 * 1024 + wg * 4 + j0 + 1];
    b1v1.z = b1[2 * 1024 + wg * 4 + j0 + 1];
    b1v1.w = b1[3 * 1024 + wg * 4 + j0 + 1];
  }

  // producer u32 base: (wg>>3)*2048 + (b>>4)*512 + (wg&1)*256 + ((wg>>1)&3)*64 + (b&15)*4
  const unsigned pcbu = ((unsigned)(wg >> 3) << 11) + ((unsigned)(wg & 1) << 8) +
                        (((unsigned)(wg >> 1) & 3u) << 6) + ((unsigned)(lane >> 4) << 9) +
                        ((unsigned)(lane & 15) << 2);

  // K-slice MFMA fronts (PLAIN cached uint4 loads — 1 KB/wave/instr)
  auto l0 = [&](const unsigned* hs, f4v* acc0, f4v* accw) {
    const uint4* hb4 = (const uint4*)hs;
#pragma unroll
    for (int ch = 0; ch < 4; ++ch) {
      const uint4* p = hb4 + (((wv << 2) + ch) << 9) + lane;
      uint4 qa[4], qb[4];
#pragma unroll
      for (int t = 0; t < 4; ++t) { qa[t] = p[t << 7]; qb[t] = p[(t << 7) + 64]; }
#pragma unroll
      for (int t = 0; t < 4; ++t) {
        s8v bh, bl; unpack8v(qa[t], qb[t], bh, bl);
        acc0[t] = MFMA(a0h[ch], bh, acc0[t]);
        accw[t] = MFMA(a1h[ch], bh, accw[t]);
        acc0[t] = MFMA(a0l[ch], bh, acc0[t]);
        accw[t] = MFMA(a1l[ch], bh, accw[t]);
        acc0[t] = MFMA(a0h[ch], bl, acc0[t]);
        accw[t] = MFMA(a1h[ch], bl, accw[t]);
      }
    }
  };
  auto l1 = [&](const unsigned* hs, f4v* acc) {
    const uint4* hb4 = (const uint4*)hs;
#pragma unroll
    for (int ch = 0; ch < 4; ++ch) {
      const uint4* p = hb4 + (((wv << 2) + ch) << 9) + lane;
      uint4 qa[4], qb[4];
#pragma unroll
      for (int t = 0; t < 4; ++t) { qa[t] = p[t << 7]; qb[t] = p[(t << 7) + 64]; }
#pragma unroll
      for (int t = 0; t < 4; ++t) {
        s8v bh, bl; unpack8v(qa[t], qb[t], bh, bl);
        acc[t] = MFMA(a1h[4 + ch], bh, acc[t]);
        acc[t] = MFMA(a1l[4 + ch], bh, acc[t]);
        acc[t] = MFMA(a1h[4 + ch], bl, acc[t]);
      }
    }
  };

  for (int ss = 0; ss <= TT; ++ss) {
    const int s0w = ss % 3, s0r = (ss + 2) % 3;         // h0 slots
    const int s1w = (ss + 2) % 3, s1r = (ss + 1) % 3;   // h1 slots

    // tz prefetch (layer-0 updater waves only; independent of all gens)
    f4v tz0 = {0.f, 0.f, 0.f, 0.f}, tz1 = {0.f, 0.f, 0.f, 0.f};
    if ((wv == 4 || wv == 5) && ss < TT) {
      size_t base = (size_t)tokens[lane * TT + ss] * 1024 + (wg << 2);
      tz0 = ((const f4v*)tz)[base + j0];
      tz1 = ((const f4v*)tz)[base + j0 + 1];
    }

    // ======== phase h0: acc0 = U0*h0(ss-1), accw = W1*h0(ss-1) ========
    pollgen(cbA + 576 + wv * 16, (unsigned)ss);
    f4v acc0[4], accw[4];
#pragma unroll
    for (int t = 0; t < 4; ++t) { acc0[t] = (f4v){0,0,0,0}; accw[t] = (f4v){0,0,0,0}; }
    l0(h0w + s0r * HSZ, acc0, accw);
#pragma unroll
    for (int t = 0; t < 4; ++t)
#pragma unroll
      for (int r = 0; r < 4; ++r)
        zpf[0][r * 2080 + quad * 520 + wv * 65 + t * 16 + n] = acc0[t][r];
    __syncthreads();

    if (ss < TT && (wv == 4 || wv == 5)) {
      // ---- tail0 (layer-0 update for units j0, j0+1; batch = lane) ----
      f4v s0 = tz0, s1 = tz1;
      const float* zb = zpf[0];
#pragma unroll
      for (int g = 0; g < 4; ++g) {
        float x0 = 0.f, x1 = 0.f;
#pragma unroll
        for (int w = 0; w < 8; ++w) {
          x0 += zb[g * 2080 + j0 * 520 + w * 65 + lane];
          x1 += zb[g * 2080 + (j0 + 1) * 520 + w * 65 + lane];
        }
        s0[g] += x0; s1[g] += x1;
      }
      float hA, hB;
      {
        float iG = sigm(s0.x), fG = sigm(s0.y), gG = tanha(s0.z), oG = sigm(s0.w);
        cA0 = fG * cA0 + iG * gG; hA = oG * tanha(cA0);
      }
      {
        float iG = sigm(s1.x), fG = sigm(s1.y), gG = tanha(s1.z), oG = sigm(s1.w);
        cB0 = fG * cB0 + iG * gG; hB = oG * tanha(cB0);
      }
      unsigned hiA = (unsigned)f2bf(hA);
      unsigned pA = (hiA << 16) | (unsigned)f2bf(hA - __uint_as_float(hiA << 16));
      unsigned hiB = (unsigned)f2bf(hB);
      unsigned pB = (hiB << 16) | (unsigned)f2bf(hB - __uint_as_float(hiB << 16));
      u64* p = (u64*)(h0w + s0w * HSZ) + (pcbu >> 1) + (wv & 1);
      stsc(p, (u64)pA | ((u64)pB << 32));
      asm volatile("s_waitcnt vmcnt(0)" ::: "memory");
      if (lane == 0) arrive2(cbA, grp);
    }

    // ======== phase h1: accw += U1*h1(ss-2); layer-1 gates ========
    if (ss >= 1) {
      pollgen(cbB + 576 + wv * 16, (unsigned)(ss - 1));
      // one L1+L2 invalidate per WG per step: after poll B, every slot read
      // from here until the next inv is fully published at MALL -> all
      // post-inv cache fills are fresh. No drain of other waves' pipes.
      if (wv == 0)
        asm volatile("s_waitcnt vmcnt(0)\n\tbuffer_inv sc1" ::: "memory");
      __syncthreads();
      l1(h1w + s1r * HSZ, accw);
#pragma unroll
      for (int t = 0; t < 4; ++t)
#pragma unroll
        for (int r = 0; r < 4; ++r)
          zpf[1][r * 2080 + quad * 520 + wv * 65 + t * 16 + n] = accw[t][r];
      __syncthreads();

      if (wv >= 6) {
        // ---- tail1 (layer-1 update for units j0, j0+1; batch = lane) ----
        f4v s0 = b1v0, s1 = b1v1;
        const float* zb = zpf[1];
#pragma unroll
        for (int g = 0; g < 4; ++g) {
          float x0 = 0.f, x1 = 0.f;
#pragma unroll
          for (int w = 0; w < 8; ++w) {
            x0 += zb[g * 2080 + j0 * 520 + w * 65 + lane];
            x1 += zb[g * 2080 + (j0 + 1) * 520 + w * 65 + lane];
          }
          s0[g] += x0; s1[g] += x1;
        }
        float hA, hB;
        {
          float iG = sigm(s0.x), fG = sigm(s0.y), gG = tanha(s0.z), oG = sigm(s0.w);
          cA1 = fG * cA1 + iG * gG; hA = oG * tanha(cA1);
        }
        {
          float iG = sigm(s1.x), fG = sigm(s1.y), gG = tanha(s1.z), oG = sigm(s1.w);
          cB1 = fG * cB1 + iG * gG; hB = oG * tanha(cB1);
        }
        unsigned hiA = (unsigned)f2bf(hA);
        unsigned pA = (hiA << 16) | (unsigned)f2bf(hA - __uint_as_float(hiA << 16));
        unsigned hiB = (unsigned)f2bf(hB);
        unsigned pB = (hiB << 16) | (unsigned)f2bf(hB - __uint_as_float(hiB << 16));
        u64* p = (u64*)(h1w + s1w * HSZ) + (pcbu >> 1) + (wv & 1);
        stsc(p, (u64)pA | ((u64)pB << 32));
        asm volatile("s_waitcnt vmcnt(0)" ::: "memory");
        if (lane == 0) arrive2(cbB, grp);
        // out store: nontemporal (keeps L2 free of dirty lines for buffer_inv)
        f2v ov; ov.x = hA; ov.y = hB;
        __builtin_nontemporal_store(ov,
            (f2v*)&out[(size_t)lane * (TT * UU) + (size_t)(ss - 1) * UU + (wg << 2) + j0]);
      }
    } else {
      // ss==0: no phase h1 — still need a sync so zpf[0] isn't rewritten
      // by fast waves before tail0 reads it
      __syncthreads();
    }
  }
}

// ---------------- host ----------------
extern "C" void kernel_launch(void* const* d_in, const int* in_sizes, int n_in,
                              void* d_out, int out_size, void* d_ws, size_t ws_size,
                              hipStream_t stream) {
  const int*   tokens = (const int*)d_in[0];
  const float* embed  = (const float*)d_in[1];
  const float* W0     = (const float*)d_in[2];
  const float* U0     = (const float*)d_in[3];
  const float* b0     = (const float*)d_in[4];
  const float* W1     = (const float*)d_in[5];
  const float* U1     = (const float*)d_in[6];
  const float* b1     = (const float*)d_in[7];
  char* ws = (char*)d_ws;
  float*          tz  = (float*)(ws + B_TZ);
  unsigned short* A0h = (unsigned short*)(ws + B_A0H);
  unsigned short* A0l = (unsigned short*)(ws + B_A0L);
  unsigned short* A1h = (unsigned short*)(ws + B_A1H);
  unsigned short* A1l = (unsigned short*)(ws + B_A1L);
  unsigned*       h0w = (unsigned*)(ws + B_H0);
  unsigned*       h1w = (unsigned*)(ws + B_H1);
  unsigned*       bar = (unsigned*)(ws + B_BAR);
  float* out = (float*)d_out;

  // zero h slots + barrier block (ws poisoned 0xAA before every call)
  hipMemsetAsync(ws + B_H0, 0, (size_t)(6ull * HSZ * 4ull + 16384ull), stream);

  pack_a0_k<<<16384, 256, 0, stream>>>(U0, A0h, A0l);
  pack_a1_k<<<32768, 256, 0, stream>>>(W1, U1, A1h, A1l);
  tz_gemm_k<<<dim3(64, 16), 256, 0, stream>>>(embed, W0, b0, tz);

  void* args[] = {(void*)&tokens, (void*)&tz, (void*)&A0h, (void*)&A0l,
                  (void*)&A1h, (void*)&A1l, (void*)&b1, (void*)&h0w, (void*)&h1w,
                  (void*)&out, (void*)&bar};
  hipLaunchCooperativeKernel((void*)lstm_coop_k, dim3(256), dim3(512), args, 0, stream);
}